// Round 21
// baseline (762.884 us; speedup 1.0000x reference)
//
#include <hip/hip_runtime.h>
#include <stdint.h>

#define D 128
#define K 512
#define HW 4096
#define NPIX 262144
#define OUT_NORM_ELEMS 33554432
#define MARGIN 0.005f
#define EPS 1e-12f
#define LOSCALE 2048.0f
#define RSCALE (1.0f / 2048.0f)

typedef _Float16 f16x8 __attribute__((ext_vector_type(8)));
typedef float f32x4 __attribute__((ext_vector_type(4)));
typedef float f32x2 __attribute__((ext_vector_type(2)));

#define FENCE() asm volatile("" ::: "memory")

__device__ __forceinline__ short f2h(float f) {
    _Float16 h = (_Float16)f; return *reinterpret_cast<short*>(&h);
}
__device__ __forceinline__ float h2f(short s) {
    _Float16 h = *reinterpret_cast<_Float16*>(&s); return (float)h;
}

__global__ void zero_kernel(float* __restrict__ p, int n) {
    int i = blockIdx.x * blockDim.x + threadIdx.x;
    if (i < n) p[i] = 0.0f;
}

// One wave per centroid: fp32 normalize; store fp16 hi + 2048-scaled fp16 lo
// ([k][256] halfs: 0..127 hi, 128..255 lo'); nc = sum(c_norm^2) fp32.
__global__ void normalize_centroids(const float* __restrict__ c,
                                    short* __restrict__ csp,
                                    float* __restrict__ nc) {
    int k = blockIdx.x * 4 + (threadIdx.x >> 6);
    int lane = threadIdx.x & 63;
    float2 v = *(const float2*)(c + (size_t)k * D + lane * 2);
    float ss = v.x * v.x + v.y * v.y;
    #pragma unroll
    for (int off = 32; off; off >>= 1) ss += __shfl_xor(ss, off);
    float rinv = 1.0f / fmaxf(sqrtf(ss), EPS);
    float ox = v.x * rinv, oy = v.y * rinv;
    short hx = f2h(ox), hy = f2h(oy);
    short lx = f2h((ox - h2f(hx)) * LOSCALE);
    short ly = f2h((oy - h2f(hy)) * LOSCALE);
    *(short2*)&csp[(size_t)k * 256 + 2 * lane]       = make_short2(hx, hy);
    *(short2*)&csp[(size_t)k * 256 + 128 + 2 * lane] = make_short2(lx, ly);
    float ss2 = ox * ox + oy * oy;
    #pragma unroll
    for (int off = 32; off; off >>= 1) ss2 += __shfl_xor(ss2, off);
    if (lane == 0) nc[k] = ss2;
}

// K1: single-x-pass normalize + transpose. 512 thr, 256 px/block, full
// 256x128 tile in LDS (stride 129). Writes out_norm (d-major, coalesced)
// and rows[px][128] RAW (pixel-major, coalesced).  [proven round 19]
#define K1S 129
__global__ __launch_bounds__(512) void normalize_x(
    const float* __restrict__ x, float* __restrict__ out_norm,
    float* __restrict__ rows, int prim)
{
    __shared__ float xt[256 * K1S];    // 132096 B
    __shared__ float rinv_s[256];
    const int t = threadIdx.x;
    const int pix0 = blockIdx.x * 256;
    const int b = pix0 >> 12;
    const int p0 = pix0 & (HW - 1);
    const float* xg = x + (size_t)b * (D * HW) + p0;
    float* og = out_norm + (size_t)b * (D * HW) + p0;

    if (prim) {
        #pragma unroll 8
        for (int s = 0; s < 32; ++s) {
            int gid = s * 512 + t;
            int d = gid >> 7;
            int px2 = (gid & 127) * 2;
            f32x2 v = *(const f32x2*)(xg + (size_t)d * HW + px2);
            xt[(px2 + 0) * K1S + d] = v.x;
            xt[(px2 + 1) * K1S + d] = v.y;
        }
        __syncthreads();
        {
            int px = t >> 1, half = t & 1;
            float ss = 0.f;
            #pragma unroll 16
            for (int i = 0; i < 64; ++i) {
                float v = xt[px * K1S + half * 64 + i];
                ss += v * v;
            }
            ss += __shfl_xor(ss, 1);
            if (half == 0) rinv_s[px] = 1.f / fmaxf(sqrtf(ss), EPS);
        }
        __syncthreads();
        #pragma unroll 8
        for (int s = 0; s < 64; ++s) {
            int idx = s * 512 + t;
            int d = idx >> 8;
            int px = idx & 255;
            og[(size_t)d * HW + px] = xt[px * K1S + d] * rinv_s[px];
        }
        #pragma unroll 8
        for (int s = 0; s < 64; ++s) {
            int idx = s * 512 + t;
            int px = idx >> 7;
            int c = idx & 127;
            rows[(size_t)(pix0 + px) * 128 + c] = xt[px * K1S + c];
        }
    } else {
        int px = t >> 1, half = t & 1;
        const float* xp = xg + px;
        float ss = 0.f;
        #pragma unroll 16
        for (int d = 0; d < 64; ++d) {
            float v = xp[(size_t)(half * 64 + d) * HW];
            ss += v * v;
        }
        ss += __shfl_xor(ss, 1);
        float rinv = 1.f / fmaxf(sqrtf(ss), EPS);
        #pragma unroll 16
        for (int d = 0; d < 64; ++d) {
            float v = xp[(size_t)(half * 64 + d) * HW];
            og[(size_t)(half * 64 + d) * HW + px] = v * rinv;
        }
    }
}

// top-2 update: d2 via clamp idiom (v_med3_f32: d1<=d2 invariant holds)
#define UPD(dd, cc, ri) do {                                      \
    bool lt1 = (dd) < d1[ri];                                     \
    d2[ri] = fminf(fmaxf((dd), d1[ri]), d2[ri]);                  \
    i1[ri] = lt1 ? (cc) : i1[ri];                                 \
    d1[ri] = fminf((dd), d1[ri]);                                 \
} while (0)

// K2: distance GEMM + online top-2 + idx/mask. Round-20 proven body
// (256 thr = 4 waves x 32 px, 128 px/block), ring-3 LDS (26.6 KB ->
// 6 blocks/CU = 24 waves, was 4/16). Stage for chunk c+2 issued AFTER
// the barrier of chunk c: at that barrier every wave has finished
// reading chunk c-1 = buffer (c+2)%3, so depth-2 prefetch is race-free
// with only 3 buffers. vmcnt(2) per iter (only stage(c+1) outstanding).
#define SMBUF 8192
#define SMNC  24576
#define SM2_BYTES 26624
__global__ __launch_bounds__(256, 6) void gemm_top2(
    const float* __restrict__ xn, const float* __restrict__ rows,
    const short* __restrict__ csp, const float* __restrict__ nc,
    float* __restrict__ oidx, int* __restrict__ pixinfo, int prim)
{
    __shared__ char smem[SM2_BYTES] __attribute__((aligned(16)));
    float* nc_s = (float*)(smem + SMNC);

    const int t = threadIdx.x;
    const int lane = t & 63;
    const int wid = t >> 6;                  // 0..3
    const int lb15 = lane & 15;
    const int kl4 = lane >> 4;
    const int kl = kl4 * 16;
    const int lswzB = lb15 << 4;             // full-row swizzle (bits 4-7)
    const int pix0 = blockIdx.x * 128;

    nc_s[t] = nc[t];
    nc_s[t + 256] = nc[t + 256];

    auto stageB = [&](int bufoff, int cb) {  // one 16-centroid chunk -> 8 KB
        const char* src = (const char*)csp + (size_t)cb * 512;
        #pragma unroll
        for (int r = 0; r < 2; ++r) {
            int Pl = r * 4096 + wid * 1024 + lane * 16;
            int row = Pl >> 9;
            int goff = Pl ^ ((row & 15) << 4);   // pre-swizzled source
            __builtin_amdgcn_global_load_lds(
                (const __attribute__((address_space(1))) uint32_t*)(src + goff),
                (__attribute__((address_space(3))) uint32_t*)(smem + bufoff + Pl),
                16, 0, 0);
        }
    };

    // A fragments (fp16 hi + 2048-scaled lo) for 32 px/wave
    f16x8 ahi[2][4], alo[2][4];
    if (prim) {
        #pragma unroll
        for (int mf = 0; mf < 2; ++mf) {
            const float* rp = rows + (size_t)(pix0 + wid * 32 + mf * 16 + lb15) * 128;
            f32x4 v0[4], v1[4];
            float ss = 0.f;
            #pragma unroll
            for (int kq = 0; kq < 4; ++kq) {
                v0[kq] = *(const f32x4*)(rp + kq * 32 + kl4 * 8);
                v1[kq] = *(const f32x4*)(rp + kq * 32 + kl4 * 8 + 4);
                #pragma unroll
                for (int e = 0; e < 4; ++e)
                    ss += v0[kq][e] * v0[kq][e] + v1[kq][e] * v1[kq][e];
            }
            ss += __shfl_xor(ss, 16);
            ss += __shfl_xor(ss, 32);
            float rinv = 1.f / fmaxf(sqrtf(ss), EPS);
            #pragma unroll
            for (int kq = 0; kq < 4; ++kq) {
                f16x8 h, l;
                #pragma unroll
                for (int e = 0; e < 4; ++e) {
                    float a = v0[kq][e] * rinv;
                    _Float16 hv = (_Float16)a;
                    h[e] = hv; l[e] = (_Float16)((a - (float)hv) * LOSCALE);
                    float c = v1[kq][e] * rinv;
                    _Float16 hw = (_Float16)c;
                    h[4 + e] = hw; l[4 + e] = (_Float16)((c - (float)hw) * LOSCALE);
                }
                ahi[mf][kq] = h; alo[mf][kq] = l;
            }
        }
    } else {
        #pragma unroll
        for (int mf = 0; mf < 2; ++mf) {
            int px = pix0 + wid * 32 + mf * 16 + lb15;
            const float* xp = xn + (size_t)(px >> 12) * (D * HW) + (px & (HW - 1));
            #pragma unroll
            for (int kq = 0; kq < 4; ++kq) {
                f16x8 h, l;
                #pragma unroll
                for (int e = 0; e < 8; ++e) {
                    float v = xp[(size_t)(kq * 32 + kl4 * 8 + e) * HW];
                    _Float16 hv = (_Float16)v;
                    h[e] = hv;
                    l[e] = (_Float16)((v - (float)hv) * LOSCALE);
                }
                ahi[mf][kq] = h; alo[mf][kq] = l;
            }
        }
    }
    __syncthreads();   // nc_s visibility (drains everything; prefetch not yet issued)

    stageB(0 * SMBUF, 0);     // chunk 0 -> buf 0
    stageB(1 * SMBUF, 16);    // chunk 1 -> buf 1

    float d1[8], d2[8]; int i1[8];
    #pragma unroll
    for (int r = 0; r < 8; ++r) { d1[r] = 3.4e38f; d2[r] = 3.4e38f; i1[r] = 0; }

    for (int c = 0; c < 32; ++c) {
        const int cb = c * 16;
        // wait: only stage(c+1)'s 2 loads may remain outstanding
        if (c < 31) { asm volatile("s_waitcnt vmcnt(2)" ::: "memory"); }
        else        { asm volatile("s_waitcnt vmcnt(0)" ::: "memory"); }
        __builtin_amdgcn_s_barrier();
        FENCE();
        // stage chunk c+2 into buf (c+2)%3 = (c-1)%3; every wave finished
        // reading c-1 before this barrier -> race-free with 3 buffers.
        if (c + 2 < 32) stageB(((c + 2) % 3) * SMBUF, cb + 32);
        const int bufoff = (c % 3) * SMBUF;

        f32x4 am[2], ac[2];
        #pragma unroll
        for (int mf = 0; mf < 2; ++mf) {
            am[mf] = (f32x4){0.f, 0.f, 0.f, 0.f};
            ac[mf] = (f32x4){0.f, 0.f, 0.f, 0.f};
        }

        #pragma unroll
        for (int kq = 0; kq < 4; ++kq) {
            const int rowb = lb15 * 512;
            f16x8 bh = *(const f16x8*)(smem + bufoff + rowb + ((kq * 64 + kl) ^ lswzB));
            f16x8 bl = *(const f16x8*)(smem + bufoff + rowb + ((256 + kq * 64 + kl) ^ lswzB));
            #pragma unroll
            for (int mf = 0; mf < 2; ++mf) {
                am[mf] = __builtin_amdgcn_mfma_f32_16x16x32_f16(ahi[mf][kq], bh, am[mf], 0, 0, 0);
                ac[mf] = __builtin_amdgcn_mfma_f32_16x16x32_f16(ahi[mf][kq], bl, ac[mf], 0, 0, 0);
                ac[mf] = __builtin_amdgcn_mfma_f32_16x16x32_f16(alo[mf][kq], bh, ac[mf], 0, 0, 0);
            }
        }

        {
            int cid = cb + lb15;
            float ncv = nc_s[cid];
            #pragma unroll
            for (int mf = 0; mf < 2; ++mf)
                #pragma unroll
                for (int j = 0; j < 4; ++j) {
                    int ri = mf * 4 + j;
                    float dd = ncv - 2.f * am[mf][j] - (2.f * RSCALE) * ac[mf][j];
                    UPD(dd, cid, ri);
                }
        }
        FENCE();
    }

    // butterfly merge over the 16 centroid lanes (tie -> lower idx)
    #pragma unroll
    for (int r = 0; r < 8; ++r) {
        #pragma unroll
        for (int m = 1; m < 16; m <<= 1) {
            float o1 = __shfl_xor(d1[r], m);
            float o2 = __shfl_xor(d2[r], m);
            int   oi = __shfl_xor(i1[r], m);
            bool take = (o1 < d1[r]) || (o1 == d1[r] && oi < i1[r]);
            float loser = take ? d1[r] : o1;
            d2[r] = fminf(loser, fminf(d2[r], o2));
            if (take) { d1[r] = o1; i1[r] = oi; }
        }
    }
    if (lb15 == 0) {
        #pragma unroll
        for (int mf = 0; mf < 2; ++mf)
            #pragma unroll
            for (int j = 0; j < 4; ++j) {
                int r = mf * 4 + j;
                int px = pix0 + wid * 32 + mf * 16 + kl4 * 4 + j;
                oidx[px] = (float)i1[r];
                pixinfo[px] = (d2[r] - d1[r] > MARGIN) ? i1[r] : -1;
            }
    }
}

// K3: ballot segment sum. 8 blocks/cluster; pixinfo scans L2-resident;
// matched pixels' RAW rows gathered contiguously from the f32 pixel-major
// rows buffer (prim) or strided from x (fallback). One 128-float
// atomicAdd per block.  [proven round 15]
__global__ __launch_bounds__(256) void segsum_kernel(
    const float* __restrict__ x, const float* __restrict__ rows,
    const int* __restrict__ pixinfo, float* __restrict__ csum,
    float* __restrict__ ccnt, int prim)
{
    __shared__ float psum[4 * 128];
    __shared__ int pcnt[4];
    const int kc   = blockIdx.x >> 3;
    const int oct  = blockIdx.x & 7;
    const int lane = threadIdx.x & 63;
    const int w    = threadIdx.x >> 6;
    const int base = oct * 32768 + w * 8192;

    float a0 = 0.f, a1 = 0.f;
    int cnt = 0;
    for (int it = 0; it < 128; ++it) {
        int ibase = base + it * 64;
        int v = pixinfo[ibase + lane];
        unsigned long long m = __ballot(v == kc);
        cnt += (int)__popcll(m);
        while (m) {
            int bpos = __builtin_ctzll(m);
            m &= m - 1;
            int pid = ibase + bpos;
            if (prim) {
                f32x2 r = *(const f32x2*)(rows + (size_t)pid * 128 + 2 * lane);
                a0 += r.x;
                a1 += r.y;
            } else {
                const float* xp = x + ((size_t)(pid >> 12)) * (D * HW) + (pid & (HW - 1));
                a0 += xp[(size_t)(2 * lane) * HW];
                a1 += xp[(size_t)(2 * lane + 1) * HW];
            }
        }
    }
    psum[w * 128 + 2 * lane]     = a0;
    psum[w * 128 + 2 * lane + 1] = a1;
    if (lane == 0) pcnt[w] = cnt;
    __syncthreads();
    if (threadIdx.x < 128) {
        float s = psum[threadIdx.x] + psum[128 + threadIdx.x] +
                  psum[256 + threadIdx.x] + psum[384 + threadIdx.x];
        atomicAdd(&csum[(size_t)kc * D + threadIdx.x], s);
    }
    if (threadIdx.x == 0) {
        float c = (float)(pcnt[0] + pcnt[1] + pcnt[2] + pcnt[3]);
        atomicAdd(&ccnt[kc], c);
    }
}

extern "C" void kernel_launch(void* const* d_in, const int* in_sizes, int n_in,
                              void* d_out, int out_size, void* d_ws, size_t ws_size,
                              hipStream_t stream) {
    const float* x   = (const float*)d_in[0];
    const float* cen = (const float*)d_in[1];

    float* out      = (float*)d_out;
    float* out_norm = out;                       // 33554432
    float* csum     = out + OUT_NORM_ELEMS;      // 512*128
    float* ccnt     = csum + (size_t)K * D;      // 512
    float* oidx     = ccnt + K;                  // 262144

    // ws: csp 256KB | nc 2KB | pixinfo 1MB | rows 134MB (guarded; prim=1 proven)
    char* ws = (char*)d_ws;
    short* csp     = (short*)ws;                 // [512][256] fp16 hi|lo'
    float* nc      = (float*)(ws + 262144);      // [512] f32
    int*   pixinfo = (int*)(ws + 264192);        // [262144] i32
    float* rows    = (float*)(ws + 1312768);     // [262144][128] f32 RAW (prim)
    const size_t need_prim = 1312768ull + (size_t)NPIX * D * 4;
    int prim = (ws_size >= need_prim) ? 1 : 0;

    hipLaunchKernelGGL(zero_kernel, dim3((K * D + K + 255) / 256), dim3(256), 0, stream,
                       csum, K * D + K);
    hipLaunchKernelGGL(normalize_centroids, dim3(K / 4), dim3(256), 0, stream,
                       cen, csp, nc);
    hipLaunchKernelGGL(normalize_x, dim3(NPIX / 256), dim3(512), 0, stream,
                       x, out_norm, rows, prim);
    hipLaunchKernelGGL(gemm_top2, dim3(NPIX / 128), dim3(256), 0, stream,
                       out_norm, rows, csp, nc, oidx, pixinfo, prim);
    hipLaunchKernelGGL(segsum_kernel, dim3(K * 8), dim3(256), 0, stream,
                       x, rows, pixinfo, csum, ccnt, prim);
}

// Round 22
// 284.184 us; speedup vs baseline: 2.6845x; 2.6845x over previous
//
#include <hip/hip_runtime.h>
#include <stdint.h>

#define D 128
#define K 512
#define HW 4096
#define NPIX 262144
#define OUT_NORM_ELEMS 33554432
#define MARGIN 0.005f
#define EPS 1e-12f
#define LOSCALE 2048.0f
#define RSCALE (1.0f / 2048.0f)

typedef _Float16 f16x8 __attribute__((ext_vector_type(8)));
typedef float f32x4 __attribute__((ext_vector_type(4)));
typedef float f32x2 __attribute__((ext_vector_type(2)));

#define FENCE() asm volatile("" ::: "memory")

__device__ __forceinline__ short f2h(float f) {
    _Float16 h = (_Float16)f; return *reinterpret_cast<short*>(&h);
}
__device__ __forceinline__ float h2f(short s) {
    _Float16 h = *reinterpret_cast<_Float16*>(&s); return (float)h;
}

__global__ void zero_kernel(float* __restrict__ p, int n) {
    int i = blockIdx.x * blockDim.x + threadIdx.x;
    if (i < n) p[i] = 0.0f;
}

// One wave per centroid: fp32 normalize; store fp16 hi + 2048-scaled fp16 lo
// ([k][256] halfs: 0..127 hi, 128..255 lo'); nc = sum(c_norm^2) fp32.
__global__ void normalize_centroids(const float* __restrict__ c,
                                    short* __restrict__ csp,
                                    float* __restrict__ nc) {
    int k = blockIdx.x * 4 + (threadIdx.x >> 6);
    int lane = threadIdx.x & 63;
    float2 v = *(const float2*)(c + (size_t)k * D + lane * 2);
    float ss = v.x * v.x + v.y * v.y;
    #pragma unroll
    for (int off = 32; off; off >>= 1) ss += __shfl_xor(ss, off);
    float rinv = 1.0f / fmaxf(sqrtf(ss), EPS);
    float ox = v.x * rinv, oy = v.y * rinv;
    short hx = f2h(ox), hy = f2h(oy);
    short lx = f2h((ox - h2f(hx)) * LOSCALE);
    short ly = f2h((oy - h2f(hy)) * LOSCALE);
    *(short2*)&csp[(size_t)k * 256 + 2 * lane]       = make_short2(hx, hy);
    *(short2*)&csp[(size_t)k * 256 + 128 + 2 * lane] = make_short2(lx, ly);
    float ss2 = ox * ox + oy * oy;
    #pragma unroll
    for (int off = 32; off; off >>= 1) ss2 += __shfl_xor(ss2, off);
    if (lane == 0) nc[k] = ss2;
}

// K1: single-x-pass normalize + transpose. 512 thr, 256 px/block, full
// 256x128 tile in LDS (stride 129). Writes out_norm (d-major, coalesced)
// and rows[px][128] RAW (pixel-major, coalesced).  [proven round 19]
#define K1S 129
__global__ __launch_bounds__(512) void normalize_x(
    const float* __restrict__ x, float* __restrict__ out_norm,
    float* __restrict__ rows, int prim)
{
    __shared__ float xt[256 * K1S];    // 132096 B
    __shared__ float rinv_s[256];
    const int t = threadIdx.x;
    const int pix0 = blockIdx.x * 256;
    const int b = pix0 >> 12;
    const int p0 = pix0 & (HW - 1);
    const float* xg = x + (size_t)b * (D * HW) + p0;
    float* og = out_norm + (size_t)b * (D * HW) + p0;

    if (prim) {
        #pragma unroll 8
        for (int s = 0; s < 32; ++s) {
            int gid = s * 512 + t;
            int d = gid >> 7;
            int px2 = (gid & 127) * 2;
            f32x2 v = *(const f32x2*)(xg + (size_t)d * HW + px2);
            xt[(px2 + 0) * K1S + d] = v.x;
            xt[(px2 + 1) * K1S + d] = v.y;
        }
        __syncthreads();
        {
            int px = t >> 1, half = t & 1;
            float ss = 0.f;
            #pragma unroll 16
            for (int i = 0; i < 64; ++i) {
                float v = xt[px * K1S + half * 64 + i];
                ss += v * v;
            }
            ss += __shfl_xor(ss, 1);
            if (half == 0) rinv_s[px] = 1.f / fmaxf(sqrtf(ss), EPS);
        }
        __syncthreads();
        #pragma unroll 8
        for (int s = 0; s < 64; ++s) {
            int idx = s * 512 + t;
            int d = idx >> 8;
            int px = idx & 255;
            og[(size_t)d * HW + px] = xt[px * K1S + d] * rinv_s[px];
        }
        #pragma unroll 8
        for (int s = 0; s < 64; ++s) {
            int idx = s * 512 + t;
            int px = idx >> 7;
            int c = idx & 127;
            rows[(size_t)(pix0 + px) * 128 + c] = xt[px * K1S + c];
        }
    } else {
        int px = t >> 1, half = t & 1;
        const float* xp = xg + px;
        float ss = 0.f;
        #pragma unroll 16
        for (int d = 0; d < 64; ++d) {
            float v = xp[(size_t)(half * 64 + d) * HW];
            ss += v * v;
        }
        ss += __shfl_xor(ss, 1);
        float rinv = 1.f / fmaxf(sqrtf(ss), EPS);
        #pragma unroll 16
        for (int d = 0; d < 64; ++d) {
            float v = xp[(size_t)(half * 64 + d) * HW];
            og[(size_t)(half * 64 + d) * HW + px] = v * rinv;
        }
    }
}

#define UPD(dd, cc, ri) do {                                      \
    bool lt1 = (dd) < d1[ri];                                     \
    float nd2 = lt1 ? d1[ri] : (((dd) < d2[ri]) ? (dd) : d2[ri]); \
    i1[ri] = lt1 ? (cc) : i1[ri];                                 \
    d1[ri] = lt1 ? (dd) : d1[ri];                                 \
    d2[ri] = nd2;                                                 \
} while (0)

// K2: distance GEMM + online top-2 + idx/mask. Round-20 proven body
// (256 thr = 4 waves x 32 px, 128 px/block), ring-3 LDS (26.6 KB ->
// 6 blocks/CU by LDS; VGPR 64 -> not register-capped). NOTE launch_bounds
// (256,4): round 21 proved (256,6) forces VGPR 64->40 => scratch spill
// (FETCH 1.7GB, 583us). Stage for chunk c+2 issued AFTER the barrier of
// chunk c (all waves finished reading buf (c+2)%3 = chunk c-1), so
// depth-2 prefetch is race-free with 3 buffers. vmcnt(2) per iter.
#define SMBUF 8192
#define SMNC  24576
#define SM2_BYTES 26624
__global__ __launch_bounds__(256, 4) void gemm_top2(
    const float* __restrict__ xn, const float* __restrict__ rows,
    const short* __restrict__ csp, const float* __restrict__ nc,
    float* __restrict__ oidx, int* __restrict__ pixinfo, int prim)
{
    __shared__ char smem[SM2_BYTES] __attribute__((aligned(16)));
    float* nc_s = (float*)(smem + SMNC);

    const int t = threadIdx.x;
    const int lane = t & 63;
    const int wid = t >> 6;                  // 0..3
    const int lb15 = lane & 15;
    const int kl4 = lane >> 4;
    const int kl = kl4 * 16;
    const int lswzB = lb15 << 4;             // full-row swizzle (bits 4-7)
    const int pix0 = blockIdx.x * 128;

    nc_s[t] = nc[t];
    nc_s[t + 256] = nc[t + 256];

    auto stageB = [&](int bufoff, int cb) {  // one 16-centroid chunk -> 8 KB
        const char* src = (const char*)csp + (size_t)cb * 512;
        #pragma unroll
        for (int r = 0; r < 2; ++r) {
            int Pl = r * 4096 + wid * 1024 + lane * 16;
            int row = Pl >> 9;
            int goff = Pl ^ ((row & 15) << 4);   // pre-swizzled source
            __builtin_amdgcn_global_load_lds(
                (const __attribute__((address_space(1))) uint32_t*)(src + goff),
                (__attribute__((address_space(3))) uint32_t*)(smem + bufoff + Pl),
                16, 0, 0);
        }
    };

    // A fragments (fp16 hi + 2048-scaled lo) for 32 px/wave
    f16x8 ahi[2][4], alo[2][4];
    if (prim) {
        #pragma unroll
        for (int mf = 0; mf < 2; ++mf) {
            const float* rp = rows + (size_t)(pix0 + wid * 32 + mf * 16 + lb15) * 128;
            f32x4 v0[4], v1[4];
            float ss = 0.f;
            #pragma unroll
            for (int kq = 0; kq < 4; ++kq) {
                v0[kq] = *(const f32x4*)(rp + kq * 32 + kl4 * 8);
                v1[kq] = *(const f32x4*)(rp + kq * 32 + kl4 * 8 + 4);
                #pragma unroll
                for (int e = 0; e < 4; ++e)
                    ss += v0[kq][e] * v0[kq][e] + v1[kq][e] * v1[kq][e];
            }
            ss += __shfl_xor(ss, 16);
            ss += __shfl_xor(ss, 32);
            float rinv = 1.f / fmaxf(sqrtf(ss), EPS);
            #pragma unroll
            for (int kq = 0; kq < 4; ++kq) {
                f16x8 h, l;
                #pragma unroll
                for (int e = 0; e < 4; ++e) {
                    float a = v0[kq][e] * rinv;
                    _Float16 hv = (_Float16)a;
                    h[e] = hv; l[e] = (_Float16)((a - (float)hv) * LOSCALE);
                    float c = v1[kq][e] * rinv;
                    _Float16 hw = (_Float16)c;
                    h[4 + e] = hw; l[4 + e] = (_Float16)((c - (float)hw) * LOSCALE);
                }
                ahi[mf][kq] = h; alo[mf][kq] = l;
            }
        }
    } else {
        #pragma unroll
        for (int mf = 0; mf < 2; ++mf) {
            int px = pix0 + wid * 32 + mf * 16 + lb15;
            const float* xp = xn + (size_t)(px >> 12) * (D * HW) + (px & (HW - 1));
            #pragma unroll
            for (int kq = 0; kq < 4; ++kq) {
                f16x8 h, l;
                #pragma unroll
                for (int e = 0; e < 8; ++e) {
                    float v = xp[(size_t)(kq * 32 + kl4 * 8 + e) * HW];
                    _Float16 hv = (_Float16)v;
                    h[e] = hv;
                    l[e] = (_Float16)((v - (float)hv) * LOSCALE);
                }
                ahi[mf][kq] = h; alo[mf][kq] = l;
            }
        }
    }
    __syncthreads();   // nc_s visibility (drains everything; prefetch not yet issued)

    stageB(0 * SMBUF, 0);     // chunk 0 -> buf 0
    stageB(1 * SMBUF, 16);    // chunk 1 -> buf 1

    float d1[8], d2[8]; int i1[8];
    #pragma unroll
    for (int r = 0; r < 8; ++r) { d1[r] = 3.4e38f; d2[r] = 3.4e38f; i1[r] = 0; }

    for (int c = 0; c < 32; ++c) {
        const int cb = c * 16;
        // wait: only stage(c+1)'s 2 loads may remain outstanding
        if (c < 31) { asm volatile("s_waitcnt vmcnt(2)" ::: "memory"); }
        else        { asm volatile("s_waitcnt vmcnt(0)" ::: "memory"); }
        __builtin_amdgcn_s_barrier();
        FENCE();
        // stage chunk c+2 into buf (c+2)%3 = (c-1)%3; every wave finished
        // reading c-1 before this barrier -> race-free with 3 buffers.
        if (c + 2 < 32) stageB(((c + 2) % 3) * SMBUF, cb + 32);
        const int bufoff = (c % 3) * SMBUF;

        f32x4 am[2], ac[2];
        #pragma unroll
        for (int mf = 0; mf < 2; ++mf) {
            am[mf] = (f32x4){0.f, 0.f, 0.f, 0.f};
            ac[mf] = (f32x4){0.f, 0.f, 0.f, 0.f};
        }

        #pragma unroll
        for (int kq = 0; kq < 4; ++kq) {
            const int rowb = lb15 * 512;
            f16x8 bh = *(const f16x8*)(smem + bufoff + rowb + ((kq * 64 + kl) ^ lswzB));
            f16x8 bl = *(const f16x8*)(smem + bufoff + rowb + ((256 + kq * 64 + kl) ^ lswzB));
            #pragma unroll
            for (int mf = 0; mf < 2; ++mf) {
                am[mf] = __builtin_amdgcn_mfma_f32_16x16x32_f16(ahi[mf][kq], bh, am[mf], 0, 0, 0);
                ac[mf] = __builtin_amdgcn_mfma_f32_16x16x32_f16(ahi[mf][kq], bl, ac[mf], 0, 0, 0);
                ac[mf] = __builtin_amdgcn_mfma_f32_16x16x32_f16(alo[mf][kq], bh, ac[mf], 0, 0, 0);
            }
        }

        {
            int cid = cb + lb15;
            float ncv = nc_s[cid];
            #pragma unroll
            for (int mf = 0; mf < 2; ++mf)
                #pragma unroll
                for (int j = 0; j < 4; ++j) {
                    int ri = mf * 4 + j;
                    float dd = ncv - 2.f * am[mf][j] - (2.f * RSCALE) * ac[mf][j];
                    UPD(dd, cid, ri);
                }
        }
        FENCE();
    }

    // butterfly merge over the 16 centroid lanes (tie -> lower idx)
    #pragma unroll
    for (int r = 0; r < 8; ++r) {
        #pragma unroll
        for (int m = 1; m < 16; m <<= 1) {
            float o1 = __shfl_xor(d1[r], m);
            float o2 = __shfl_xor(d2[r], m);
            int   oi = __shfl_xor(i1[r], m);
            bool take = (o1 < d1[r]) || (o1 == d1[r] && oi < i1[r]);
            float loser = take ? d1[r] : o1;
            d2[r] = fminf(loser, fminf(d2[r], o2));
            if (take) { d1[r] = o1; i1[r] = oi; }
        }
    }
    if (lb15 == 0) {
        #pragma unroll
        for (int mf = 0; mf < 2; ++mf)
            #pragma unroll
            for (int j = 0; j < 4; ++j) {
                int r = mf * 4 + j;
                int px = pix0 + wid * 32 + mf * 16 + kl4 * 4 + j;
                oidx[px] = (float)i1[r];
                pixinfo[px] = (d2[r] - d1[r] > MARGIN) ? i1[r] : -1;
            }
    }
}

// K3: ballot segment sum. 8 blocks/cluster; pixinfo scans L2-resident;
// matched pixels' RAW rows gathered contiguously from the f32 pixel-major
// rows buffer (prim) or strided from x (fallback). One 128-float
// atomicAdd per block.  [proven round 15]
__global__ __launch_bounds__(256) void segsum_kernel(
    const float* __restrict__ x, const float* __restrict__ rows,
    const int* __restrict__ pixinfo, float* __restrict__ csum,
    float* __restrict__ ccnt, int prim)
{
    __shared__ float psum[4 * 128];
    __shared__ int pcnt[4];
    const int kc   = blockIdx.x >> 3;
    const int oct  = blockIdx.x & 7;
    const int lane = threadIdx.x & 63;
    const int w    = threadIdx.x >> 6;
    const int base = oct * 32768 + w * 8192;

    float a0 = 0.f, a1 = 0.f;
    int cnt = 0;
    for (int it = 0; it < 128; ++it) {
        int ibase = base + it * 64;
        int v = pixinfo[ibase + lane];
        unsigned long long m = __ballot(v == kc);
        cnt += (int)__popcll(m);
        while (m) {
            int bpos = __builtin_ctzll(m);
            m &= m - 1;
            int pid = ibase + bpos;
            if (prim) {
                f32x2 r = *(const f32x2*)(rows + (size_t)pid * 128 + 2 * lane);
                a0 += r.x;
                a1 += r.y;
            } else {
                const float* xp = x + ((size_t)(pid >> 12)) * (D * HW) + (pid & (HW - 1));
                a0 += xp[(size_t)(2 * lane) * HW];
                a1 += xp[(size_t)(2 * lane + 1) * HW];
            }
        }
    }
    psum[w * 128 + 2 * lane]     = a0;
    psum[w * 128 + 2 * lane + 1] = a1;
    if (lane == 0) pcnt[w] = cnt;
    __syncthreads();
    if (threadIdx.x < 128) {
        float s = psum[threadIdx.x] + psum[128 + threadIdx.x] +
                  psum[256 + threadIdx.x] + psum[384 + threadIdx.x];
        atomicAdd(&csum[(size_t)kc * D + threadIdx.x], s);
    }
    if (threadIdx.x == 0) {
        float c = (float)(pcnt[0] + pcnt[1] + pcnt[2] + pcnt[3]);
        atomicAdd(&ccnt[kc], c);
    }
}

extern "C" void kernel_launch(void* const* d_in, const int* in_sizes, int n_in,
                              void* d_out, int out_size, void* d_ws, size_t ws_size,
                              hipStream_t stream) {
    const float* x   = (const float*)d_in[0];
    const float* cen = (const float*)d_in[1];

    float* out      = (float*)d_out;
    float* out_norm = out;                       // 33554432
    float* csum     = out + OUT_NORM_ELEMS;      // 512*128
    float* ccnt     = csum + (size_t)K * D;      // 512
    float* oidx     = ccnt + K;                  // 262144

    // ws: csp 256KB | nc 2KB | pixinfo 1MB | rows 134MB (guarded; prim=1 proven)
    char* ws = (char*)d_ws;
    short* csp     = (short*)ws;                 // [512][256] fp16 hi|lo'
    float* nc      = (float*)(ws + 262144);      // [512] f32
    int*   pixinfo = (int*)(ws + 264192);        // [262144] i32
    float* rows    = (float*)(ws + 1312768);     // [262144][128] f32 RAW (prim)
    const size_t need_prim = 1312768ull + (size_t)NPIX * D * 4;
    int prim = (ws_size >= need_prim) ? 1 : 0;

    hipLaunchKernelGGL(zero_kernel, dim3((K * D + K + 255) / 256), dim3(256), 0, stream,
                       csum, K * D + K);
    hipLaunchKernelGGL(normalize_centroids, dim3(K / 4), dim3(256), 0, stream,
                       cen, csp, nc);
    hipLaunchKernelGGL(normalize_x, dim3(NPIX / 256), dim3(512), 0, stream,
                       x, out_norm, rows, prim);
    hipLaunchKernelGGL(gemm_top2, dim3(NPIX / 128), dim3(256), 0, stream,
                       out_norm, rows, csp, nc, oidx, pixinfo, prim);
    hipLaunchKernelGGL(segsum_kernel, dim3(K * 8), dim3(256), 0, stream,
                       x, rows, pixinfo, csum, ccnt, prim);
}